// Round 1
// baseline (357.268 us; speedup 1.0000x reference)
//
#include <hip/hip_runtime.h>
#include <hip/hip_bf16.h>

// Problem constants (B=2, T=2048, C=1024, H=16, d=64)
#define BB 2
#define TT 2048
#define CC 1024
#define HH 16
#define DD 64
#define MM (BB*TT)   // 4096 rows

typedef __bf16 bf16x8 __attribute__((ext_vector_type(8)));
typedef float f32x4 __attribute__((ext_vector_type(4)));

// ---------------------------------------------------------------------------
// x (fp32) -> bf16, vectorized 4-wide
__global__ __launch_bounds__(256)
void conv_bf16(const float* __restrict__ in, __hip_bfloat16* __restrict__ out, int n4) {
    int i = blockIdx.x * 256 + threadIdx.x;
    if (i >= n4) return;
    float4 f = reinterpret_cast<const float4*>(in)[i];
    union { __hip_bfloat16 h[4]; uint2 u; } cv;
    cv.h[0] = __float2bfloat16(f.x);
    cv.h[1] = __float2bfloat16(f.y);
    cv.h[2] = __float2bfloat16(f.z);
    cv.h[3] = __float2bfloat16(f.w);
    reinterpret_cast<uint2*>(out)[i] = cv.u;
}

// W (CxC fp32, row-major [k][n]) -> Wt (bf16, [n][k]) via LDS tile transpose
__global__ __launch_bounds__(256)
void transpose_conv(const float* __restrict__ W, __hip_bfloat16* __restrict__ Wt) {
    __shared__ float t[32][33];
    int kt = blockIdx.x * 32, nt = blockIdx.y * 32;
    int tx = threadIdx.x & 31, ty = threadIdx.x >> 5;  // 32 x 8
#pragma unroll
    for (int r = 0; r < 32; r += 8)
        t[ty + r][tx] = W[(size_t)(kt + ty + r) * CC + nt + tx];
    __syncthreads();
#pragma unroll
    for (int r = 0; r < 32; r += 8)
        Wt[(size_t)(nt + ty + r) * CC + kt + tx] = __float2bfloat16(t[tx][ty + r]);
}

// ---------------------------------------------------------------------------
// C[M][N] = A[M][K] @ Bt[N][K]^T   (both bf16 row-major, MFMA 16x16x32)
// 256 threads = 4 waves (2x2), tile 128x128, BK=32.
// If F32OUT: out fp32 with optional bias; else out bf16.
template <bool F32OUT>
__global__ __launch_bounds__(256)
void gemm_bt(const __hip_bfloat16* __restrict__ A,
             const __hip_bfloat16* __restrict__ Bt,
             void* __restrict__ Cout,
             const float* __restrict__ bias,
             int M, int N, int K) {
    __shared__ __hip_bfloat16 As[128 * 40];   // +8 pad: 80B row stride, 16B aligned
    __shared__ __hip_bfloat16 Bs[128 * 40];

    const int tid = threadIdx.x;
    const int wave = tid >> 6, lane = tid & 63;
    const int lg = lane >> 4, lr = lane & 15;
    const int wm = wave >> 1, wn = wave & 1;
    const int bm0 = blockIdx.y * 128, bn0 = blockIdx.x * 128;

    f32x4 acc[4][4] = {};

    for (int k0 = 0; k0 < K; k0 += 32) {
        __syncthreads();
        // stage A/B tiles: 512 chunks of 16B each (2 per thread per matrix)
#pragma unroll
        for (int c = tid; c < 512; c += 256) {
            int row = c >> 2, cb = c & 3;
            uint4 va = *reinterpret_cast<const uint4*>(&A[(size_t)(bm0 + row) * K + k0 + cb * 8]);
            *reinterpret_cast<uint4*>(&As[row * 40 + cb * 8]) = va;
            uint4 vb = *reinterpret_cast<const uint4*>(&Bt[(size_t)(bn0 + row) * K + k0 + cb * 8]);
            *reinterpret_cast<uint4*>(&Bs[row * 40 + cb * 8]) = vb;
        }
        __syncthreads();

        bf16x8 af[4], bf[4];
#pragma unroll
        for (int m = 0; m < 4; m++)
            af[m] = *reinterpret_cast<const bf16x8*>(&As[(wm * 64 + m * 16 + lr) * 40 + lg * 8]);
#pragma unroll
        for (int n = 0; n < 4; n++)
            bf[n] = *reinterpret_cast<const bf16x8*>(&Bs[(wn * 64 + n * 16 + lr) * 40 + lg * 8]);
#pragma unroll
        for (int m = 0; m < 4; m++)
#pragma unroll
            for (int n = 0; n < 4; n++)
                acc[m][n] = __builtin_amdgcn_mfma_f32_16x16x32_bf16(af[m], bf[n], acc[m][n], 0, 0, 0);
    }

    // epilogue: C/D layout col = lane&15, row = (lane>>4)*4 + reg
#pragma unroll
    for (int m = 0; m < 4; m++)
#pragma unroll
        for (int n = 0; n < 4; n++)
#pragma unroll
            for (int r = 0; r < 4; r++) {
                int row = bm0 + wm * 64 + m * 16 + lg * 4 + r;
                int col = bn0 + wn * 64 + n * 16 + lr;
                float v = acc[m][n][r];
                if (F32OUT) {
                    ((float*)Cout)[(size_t)row * N + col] = v + (bias ? bias[col] : 0.f);
                } else {
                    ((__hip_bfloat16*)Cout)[(size_t)row * N + col] = __float2bfloat16(v);
                }
            }
}

// ---------------------------------------------------------------------------
// Flash-style causal attention.
// Grid: (T/128, H, B). Block: 256 threads = 4 waves; wave w owns 32 q-rows.
// KV tiles of 64. Online softmax. P goes through per-wave LDS for A-frag layout.
__global__ __launch_bounds__(256)
void attn_kernel(const __hip_bfloat16* __restrict__ Q,
                 const __hip_bfloat16* __restrict__ K,
                 const __hip_bfloat16* __restrict__ V,
                 __hip_bfloat16* __restrict__ att) {
    __shared__ __hip_bfloat16 Kt[64 * 72];      // [kv][d], pad to 72
    __shared__ __hip_bfloat16 Vt[64 * 72];      // [d][kv], transposed
    __shared__ __hip_bfloat16 Pl[4][32 * 72];   // per-wave P: [q_local][kv]

    const int tid = threadIdx.x;
    const int wave = tid >> 6, lane = tid & 63;
    const int lg = lane >> 4, lr = lane & 15;
    const int qt = blockIdx.x, h = blockIdx.y, b = blockIdx.z;
    const size_t base = ((size_t)b * TT) * CC + (size_t)h * DD;  // elem offset of (b,h)
    const int q0 = qt * 128;
    const int wq0 = q0 + wave * 32;

    // Q fragments in registers: q rows wq0 + mf*16 + lr, d = kf*32 + lg*8 + j
    bf16x8 qf[2][2];
#pragma unroll
    for (int mf = 0; mf < 2; mf++)
#pragma unroll
        for (int kf = 0; kf < 2; kf++) {
            int row = wq0 + mf * 16 + lr;
            qf[mf][kf] = *reinterpret_cast<const bf16x8*>(&Q[base + (size_t)row * CC + kf * 32 + lg * 8]);
        }

    float m_run[2][4], l_run[2][4];
    f32x4 o[2][4] = {};
#pragma unroll
    for (int mf = 0; mf < 2; mf++)
#pragma unroll
        for (int r = 0; r < 4; r++) { m_run[mf][r] = -1e30f; l_run[mf][r] = 0.f; }

    const int nkt = qt * 2 + 2;  // covers kv in [0, q0+128)
    for (int kt = 0; kt < nkt; kt++) {
        const int kv0 = kt * 64;
        __syncthreads();
        // stage K tile [64][64] row-major; V transposed into Vt [d][kv]
#pragma unroll
        for (int c = tid; c < 512; c += 256) {
            int row = c >> 3, cb = c & 7;
            uint4 kk = *reinterpret_cast<const uint4*>(&K[base + (size_t)(kv0 + row) * CC + cb * 8]);
            *reinterpret_cast<uint4*>(&Kt[row * 72 + cb * 8]) = kk;
            uint4 vv = *reinterpret_cast<const uint4*>(&V[base + (size_t)(kv0 + row) * CC + cb * 8]);
            const __hip_bfloat16* vp = reinterpret_cast<const __hip_bfloat16*>(&vv);
#pragma unroll
            for (int j = 0; j < 8; j++) Vt[(cb * 8 + j) * 72 + row] = vp[j];
        }
        __syncthreads();

        // S = Q @ K^T  (per wave: 32 q x 64 kv)
        f32x4 s[2][4] = {};
#pragma unroll
        for (int kf = 0; kf < 2; kf++) {
            bf16x8 kfr[4];
#pragma unroll
            for (int nf = 0; nf < 4; nf++)
                kfr[nf] = *reinterpret_cast<const bf16x8*>(&Kt[(nf * 16 + lr) * 72 + kf * 32 + lg * 8]);
#pragma unroll
            for (int mf = 0; mf < 2; mf++)
#pragma unroll
                for (int nf = 0; nf < 4; nf++)
                    s[mf][nf] = __builtin_amdgcn_mfma_f32_16x16x32_bf16(qf[mf][kf], kfr[nf], s[mf][nf], 0, 0, 0);
        }

        // scale (C^-0.5 = 1/32), causal mask, online softmax
#pragma unroll
        for (int mf = 0; mf < 2; mf++) {
#pragma unroll
            for (int r = 0; r < 4; r++) {
                int qg = wq0 + mf * 16 + lg * 4 + r;
                float rmax = -1e30f;
#pragma unroll
                for (int nf = 0; nf < 4; nf++) {
                    int kvg = kv0 + nf * 16 + lr;
                    float sv = s[mf][nf][r] * 0.03125f;
                    sv = (kvg > qg) ? -1e30f : sv;
                    s[mf][nf][r] = sv;
                    rmax = fmaxf(rmax, sv);
                }
#pragma unroll
                for (int off = 1; off < 16; off <<= 1)
                    rmax = fmaxf(rmax, __shfl_xor(rmax, off, 64));
                float mold = m_run[mf][r];
                float mnew = fmaxf(mold, rmax);
                float sc = __expf(mold - mnew);
                float rsum = 0.f;
#pragma unroll
                for (int nf = 0; nf < 4; nf++) {
                    float p = __expf(s[mf][nf][r] - mnew);
                    s[mf][nf][r] = p;
                    rsum += p;
                }
#pragma unroll
                for (int off = 1; off < 16; off <<= 1)
                    rsum += __shfl_xor(rsum, off, 64);
                l_run[mf][r] = l_run[mf][r] * sc + rsum;
                m_run[mf][r] = mnew;
#pragma unroll
                for (int df = 0; df < 4; df++) o[mf][df][r] *= sc;
            }
        }

        // P -> per-wave LDS (bf16), then PV
        __hip_bfloat16* Pw = &Pl[wave][0];
#pragma unroll
        for (int mf = 0; mf < 2; mf++)
#pragma unroll
            for (int nf = 0; nf < 4; nf++)
#pragma unroll
                for (int r = 0; r < 4; r++)
                    Pw[(mf * 16 + lg * 4 + r) * 72 + nf * 16 + lr] = __float2bfloat16(s[mf][nf][r]);
        asm volatile("s_waitcnt lgkmcnt(0)" ::: "memory");

#pragma unroll
        for (int ks = 0; ks < 2; ks++) {
            bf16x8 pf[2], vf[4];
#pragma unroll
            for (int mf = 0; mf < 2; mf++)
                pf[mf] = *reinterpret_cast<const bf16x8*>(&Pw[(mf * 16 + lr) * 72 + ks * 32 + lg * 8]);
#pragma unroll
            for (int df = 0; df < 4; df++)
                vf[df] = *reinterpret_cast<const bf16x8*>(&Vt[(df * 16 + lr) * 72 + ks * 32 + lg * 8]);
#pragma unroll
            for (int mf = 0; mf < 2; mf++)
#pragma unroll
                for (int df = 0; df < 4; df++)
                    o[mf][df] = __builtin_amdgcn_mfma_f32_16x16x32_bf16(pf[mf], vf[df], o[mf][df], 0, 0, 0);
        }
    }

    // normalize + store att (bf16)
#pragma unroll
    for (int mf = 0; mf < 2; mf++)
#pragma unroll
        for (int df = 0; df < 4; df++)
#pragma unroll
            for (int r = 0; r < 4; r++) {
                int qg = wq0 + mf * 16 + lg * 4 + r;
                float v = o[mf][df][r] / l_run[mf][r];
                att[base + (size_t)qg * CC + df * 16 + lr] = __float2bfloat16(v);
            }
}

// ---------------------------------------------------------------------------
extern "C" void kernel_launch(void* const* d_in, const int* in_sizes, int n_in,
                              void* d_out, int out_size, void* d_ws, size_t ws_size,
                              hipStream_t stream) {
    const float* x  = (const float*)d_in[0];
    // d_in[1] = attention_mask: no-op in the reference (post-softmax fill not in-place)
    const float* Wq = (const float*)d_in[2];
    const float* Wk = (const float*)d_in[3];
    const float* Wv = (const float*)d_in[4];
    const float* Wp = (const float*)d_in[5];
    const float* bp = (const float*)d_in[6];
    float* out = (float*)d_out;

    __hip_bfloat16* ws  = (__hip_bfloat16*)d_ws;
    __hip_bfloat16* xb  = ws;                       // MM*CC
    __hip_bfloat16* wqt = xb  + (size_t)MM * CC;    // CC*CC each
    __hip_bfloat16* wkt = wqt + (size_t)CC * CC;
    __hip_bfloat16* wvt = wkt + (size_t)CC * CC;
    __hip_bfloat16* wpt = wvt + (size_t)CC * CC;
    __hip_bfloat16* Qb  = wpt + (size_t)CC * CC;    // MM*CC each
    __hip_bfloat16* Kb  = Qb  + (size_t)MM * CC;
    __hip_bfloat16* Vb  = Kb  + (size_t)MM * CC;
    __hip_bfloat16* att = Vb  + (size_t)MM * CC;

    // 1) conversions
    conv_bf16<<<(MM * CC / 4 + 255) / 256, 256, 0, stream>>>(x, xb, MM * CC / 4);
    dim3 tg(CC / 32, CC / 32);
    transpose_conv<<<tg, 256, 0, stream>>>(Wq, wqt);
    transpose_conv<<<tg, 256, 0, stream>>>(Wk, wkt);
    transpose_conv<<<tg, 256, 0, stream>>>(Wv, wvt);
    transpose_conv<<<tg, 256, 0, stream>>>(Wp, wpt);

    // 2) Q/K/V projections (bf16 out)
    dim3 gg(CC / 128, MM / 128);  // (8, 32)
    gemm_bt<false><<<gg, 256, 0, stream>>>(xb, wqt, Qb, nullptr, MM, CC, CC);
    gemm_bt<false><<<gg, 256, 0, stream>>>(xb, wkt, Kb, nullptr, MM, CC, CC);
    gemm_bt<false><<<gg, 256, 0, stream>>>(xb, wvt, Vb, nullptr, MM, CC, CC);

    // 3) causal attention
    dim3 ag(TT / 128, HH, BB);
    attn_kernel<<<ag, 256, 0, stream>>>(Qb, Kb, Vb, att);

    // 4) output projection + bias (fp32 out)
    gemm_bt<true><<<gg, 256, 0, stream>>>(att, wpt, out, bp, MM, CC, CC);
}

// Round 2
// 246.512 us; speedup vs baseline: 1.4493x; 1.4493x over previous
//
#include <hip/hip_runtime.h>
#include <hip/hip_bf16.h>
#include <stdint.h>

// Problem constants (B=2, T=2048, C=1024, H=16, d=64)
#define BB 2
#define TT 2048
#define CC 1024
#define HH 16
#define DD 64
#define MM (BB*TT)   // 4096 rows

typedef __bf16 bf16x8 __attribute__((ext_vector_type(8)));
typedef float f32x4 __attribute__((ext_vector_type(4)));

// async 16B global -> LDS (dest must be linear: wave-uniform base + lane*16)
__device__ __forceinline__ void load_lds16(const void* g, void* l) {
    __builtin_amdgcn_global_load_lds((const __attribute__((address_space(1))) uint32_t*)g,
                                     (__attribute__((address_space(3))) uint32_t*)l,
                                     16, 0, 0);
}

// ---------------------------------------------------------------------------
// x (fp32) -> bf16, vectorized 4-wide
__global__ __launch_bounds__(256)
void conv_bf16(const float* __restrict__ in, __hip_bfloat16* __restrict__ out, int n4) {
    int i = blockIdx.x * 256 + threadIdx.x;
    if (i >= n4) return;
    float4 f = reinterpret_cast<const float4*>(in)[i];
    union { __hip_bfloat16 h[4]; uint2 u; } cv;
    cv.h[0] = __float2bfloat16(f.x);
    cv.h[1] = __float2bfloat16(f.y);
    cv.h[2] = __float2bfloat16(f.z);
    cv.h[3] = __float2bfloat16(f.w);
    reinterpret_cast<uint2*>(out)[i] = cv.u;
}

// W (CxC fp32, row-major [k][n]) -> Wt (bf16, [n][k]) via LDS tile transpose
__global__ __launch_bounds__(256)
void transpose_conv(const float* __restrict__ W, __hip_bfloat16* __restrict__ Wt) {
    __shared__ float t[32][33];
    int kt = blockIdx.x * 32, nt = blockIdx.y * 32;
    int tx = threadIdx.x & 31, ty = threadIdx.x >> 5;  // 32 x 8
#pragma unroll
    for (int r = 0; r < 32; r += 8)
        t[ty + r][tx] = W[(size_t)(kt + ty + r) * CC + nt + tx];
    __syncthreads();
#pragma unroll
    for (int r = 0; r < 32; r += 8)
        Wt[(size_t)(nt + ty + r) * CC + kt + tx] = __float2bfloat16(t[tx][ty + r]);
}

// ---------------------------------------------------------------------------
// C[M][N] = A[M][K] @ Bt[N][K]^T, bf16, MFMA 16x16x32, tile 128x128, BK=64.
// global_load_lds width-16 staging with XOR-swizzled source (T2 both-sides).
// MODE 0: bf16 row-major out0.
// MODE 1: fused QKV (N=3072): n<1024 -> Q (out0), <2048 -> K (out1),
//         else V written transposed per-head: out2[b][h][d][T].
// MODE 2: fp32 out0 + bias.
template <int MODE>
__global__ __launch_bounds__(256)
void gemm_bt(const __hip_bfloat16* __restrict__ A,
             const __hip_bfloat16* __restrict__ Bt,
             void* __restrict__ out0, void* __restrict__ out1, void* __restrict__ out2,
             const float* __restrict__ bias,
             int M, int N, int K) {
    __shared__ __hip_bfloat16 As[128 * 64];
    __shared__ __hip_bfloat16 Bs[128 * 64];

    const int tid = threadIdx.x;
    const int wave = tid >> 6, lane = tid & 63;
    const int lg = lane >> 4, lr = lane & 15;
    const int wm = wave >> 1, wn = wave & 1;
    const int bm0 = blockIdx.y * 128, bn0 = blockIdx.x * 128;

    f32x4 acc[4][4] = {};

    for (int k0 = 0; k0 < K; k0 += 64) {
        __syncthreads();
        // stage A,B: 1024 chunks of 16B each; source col pre-swizzled by row&7
#pragma unroll
        for (int it = 0; it < 4; ++it) {
            int c = it * 256 + tid;
            int row = c >> 3, sub = c & 7;
            int g = sub ^ (row & 7);
            load_lds16((const char*)(A + (size_t)(bm0 + row) * K + k0) + g * 16,
                       (char*)As + c * 16);
        }
#pragma unroll
        for (int it = 0; it < 4; ++it) {
            int c = it * 256 + tid;
            int row = c >> 3, sub = c & 7;
            int g = sub ^ (row & 7);
            load_lds16((const char*)(Bt + (size_t)(bn0 + row) * K + k0) + g * 16,
                       (char*)Bs + c * 16);
        }
        __syncthreads();  // drains vmcnt before barrier

        bf16x8 af[2][4], bf[2][4];
#pragma unroll
        for (int kk = 0; kk < 2; ++kk) {
#pragma unroll
            for (int m = 0; m < 4; ++m) {
                int row = wm * 64 + m * 16 + lr;
                af[kk][m] = *(const bf16x8*)((const char*)As + row * 128 + (((kk * 4 + lg) ^ (row & 7)) * 16));
            }
#pragma unroll
            for (int n = 0; n < 4; ++n) {
                int row = wn * 64 + n * 16 + lr;
                bf[kk][n] = *(const bf16x8*)((const char*)Bs + row * 128 + (((kk * 4 + lg) ^ (row & 7)) * 16));
            }
        }
#pragma unroll
        for (int kk = 0; kk < 2; ++kk)
#pragma unroll
            for (int m = 0; m < 4; ++m)
#pragma unroll
                for (int n = 0; n < 4; ++n)
                    acc[m][n] = __builtin_amdgcn_mfma_f32_16x16x32_bf16(af[kk][m], bf[kk][n], acc[m][n], 0, 0, 0);
    }

    // epilogue: C/D layout col = lane&15, row = (lane>>4)*4 + reg
#pragma unroll
    for (int m = 0; m < 4; ++m)
#pragma unroll
        for (int n = 0; n < 4; ++n) {
            int row0 = bm0 + wm * 64 + m * 16 + lg * 4;
            int colf = bn0 + wn * 64 + n * 16 + lr;
            if (MODE == 0) {
#pragma unroll
                for (int r = 0; r < 4; ++r)
                    ((__hip_bfloat16*)out0)[(size_t)(row0 + r) * N + colf] = __float2bfloat16(acc[m][n][r]);
            } else if (MODE == 2) {
#pragma unroll
                for (int r = 0; r < 4; ++r)
                    ((float*)out0)[(size_t)(row0 + r) * N + colf] = acc[m][n][r] + bias[colf];
            } else {
                int which = colf >> 10, col = colf & 1023;
                if (which < 2) {
                    __hip_bfloat16* o = which ? (__hip_bfloat16*)out1 : (__hip_bfloat16*)out0;
#pragma unroll
                    for (int r = 0; r < 4; ++r)
                        o[(size_t)(row0 + r) * 1024 + col] = __float2bfloat16(acc[m][n][r]);
                } else {
                    int hh = col >> 6, dd = col & 63;
                    int bI = row0 >> 11, tt = row0 & 2047;
                    union { __hip_bfloat16 h[4]; uint2 u; } pk;
#pragma unroll
                    for (int r = 0; r < 4; ++r) pk.h[r] = __float2bfloat16(acc[m][n][r]);
                    *(uint2*)((__hip_bfloat16*)out2 + ((size_t)(bI * HH + hh) * DD + dd) * TT + tt) = pk.u;
                }
            }
        }
}

// ---------------------------------------------------------------------------
// Flash-style causal attention. Grid (T/128, H, B); b==1 flips qt for balance.
// 4 waves own 32 q-rows each; KV tiles of 64; V comes in pre-transposed
// [b][h][d][T]; K/V staged via swizzled global_load_lds.
__global__ __launch_bounds__(256)
void attn_kernel(const __hip_bfloat16* __restrict__ Q,
                 const __hip_bfloat16* __restrict__ K,
                 const __hip_bfloat16* __restrict__ Vt,
                 __hip_bfloat16* __restrict__ att) {
    __shared__ __hip_bfloat16 Ks[64 * 64];     // [kv][d], XOR-swizzled
    __shared__ __hip_bfloat16 Vs[64 * 64];     // [d][kv], XOR-swizzled
    __shared__ __hip_bfloat16 Pl[4][32 * 72];  // per-wave P: [q_local][kv], padded

    const int tid = threadIdx.x;
    const int wave = tid >> 6, lane = tid & 63;
    const int lg = lane >> 4, lr = lane & 15;
    int qt = blockIdx.x;
    const int h = blockIdx.y, b = blockIdx.z;
    if (b & 1) qt = (TT / 128 - 1) - qt;  // complement pairing -> balanced CUs
    const size_t baseQK = ((size_t)b * TT) * CC + (size_t)h * DD;
    const __hip_bfloat16* Vth = Vt + ((size_t)(b * HH + h)) * DD * TT;
    const int q0 = qt * 128;
    const int wq0 = q0 + wave * 32;

    bf16x8 qf[2][2];
#pragma unroll
    for (int mf = 0; mf < 2; ++mf)
#pragma unroll
        for (int kf = 0; kf < 2; ++kf)
            qf[mf][kf] = *(const bf16x8*)&Q[baseQK + (size_t)(wq0 + mf * 16 + lr) * CC + kf * 32 + lg * 8];

    float m_run[2][4], l_run[2][4];
    f32x4 o[2][4] = {};
#pragma unroll
    for (int mf = 0; mf < 2; ++mf)
#pragma unroll
        for (int r = 0; r < 4; ++r) { m_run[mf][r] = -1e30f; l_run[mf][r] = 0.f; }

    const int nkt = qt * 2 + 2;
    for (int kt = 0; kt < nkt; ++kt) {
        const int kv0 = kt * 64;
        __syncthreads();
        // stage K tile [64][64] and Vt tile [64][64], 512 chunks each, swizzled src
#pragma unroll
        for (int it = 0; it < 2; ++it) {
            int c = it * 256 + tid;
            int row = c >> 3, sub = c & 7;
            int g = sub ^ (row & 7);
            load_lds16((const char*)(K + baseQK + (size_t)(kv0 + row) * CC) + g * 16, (char*)Ks + c * 16);
            load_lds16((const char*)(Vth + (size_t)row * TT + kv0) + g * 16, (char*)Vs + c * 16);
        }
        __syncthreads();

        const bool active = (kv0 <= wq0 + 31);
        if (active) {
            // S = Q @ K^T
            f32x4 s[2][4] = {};
#pragma unroll
            for (int kf = 0; kf < 2; ++kf) {
                bf16x8 kfr[4];
#pragma unroll
                for (int nf = 0; nf < 4; ++nf)
                    kfr[nf] = *(const bf16x8*)((const char*)Ks + (nf * 16 + lr) * 128 + (((kf * 4 + lg) ^ (lr & 7)) * 16));
#pragma unroll
                for (int mf = 0; mf < 2; ++mf)
#pragma unroll
                    for (int nf = 0; nf < 4; ++nf)
                        s[mf][nf] = __builtin_amdgcn_mfma_f32_16x16x32_bf16(qf[mf][kf], kfr[nf], s[mf][nf], 0, 0, 0);
            }

            const bool needMask = (kv0 + 63 > wq0);
#pragma unroll
            for (int mf = 0; mf < 2; ++mf) {
#pragma unroll
                for (int r = 0; r < 4; ++r) {
                    int qg = wq0 + mf * 16 + lg * 4 + r;
                    float rmax = -1e30f;
#pragma unroll
                    for (int nf = 0; nf < 4; ++nf) {
                        float sv = s[mf][nf][r] * 0.03125f;
                        if (needMask) {
                            int kvg = kv0 + nf * 16 + lr;
                            sv = (kvg > qg) ? -1e30f : sv;
                        }
                        s[mf][nf][r] = sv;
                        rmax = fmaxf(rmax, sv);
                    }
#pragma unroll
                    for (int off = 1; off < 16; off <<= 1)
                        rmax = fmaxf(rmax, __shfl_xor(rmax, off, 64));
                    float mold = m_run[mf][r];
                    float mnew = fmaxf(mold, rmax);
                    float sc = __expf(mold - mnew);
                    float rsum = 0.f;
#pragma unroll
                    for (int nf = 0; nf < 4; ++nf) {
                        float p = __expf(s[mf][nf][r] - mnew);
                        s[mf][nf][r] = p;
                        rsum += p;
                    }
#pragma unroll
                    for (int off = 1; off < 16; off <<= 1)
                        rsum += __shfl_xor(rsum, off, 64);
                    l_run[mf][r] = l_run[mf][r] * sc + rsum;
                    m_run[mf][r] = mnew;
#pragma unroll
                    for (int df = 0; df < 4; df++) o[mf][df][r] *= sc;
                }
            }

            // P -> per-wave LDS (bf16), then PV
            __hip_bfloat16* Pw = &Pl[wave][0];
#pragma unroll
            for (int mf = 0; mf < 2; ++mf)
#pragma unroll
                for (int nf = 0; nf < 4; ++nf)
#pragma unroll
                    for (int r = 0; r < 4; ++r)
                        Pw[(mf * 16 + lg * 4 + r) * 72 + nf * 16 + lr] = __float2bfloat16(s[mf][nf][r]);

#pragma unroll
            for (int ks = 0; ks < 2; ++ks) {
                bf16x8 pf[2], vf[4];
#pragma unroll
                for (int mf = 0; mf < 2; ++mf)
                    pf[mf] = *(const bf16x8*)&Pw[(mf * 16 + lr) * 72 + ks * 32 + lg * 8];
#pragma unroll
                for (int df = 0; df < 4; ++df)
                    vf[df] = *(const bf16x8*)((const char*)Vs + (df * 16 + lr) * 128 + (((ks * 4 + lg) ^ (lr & 7)) * 16));
#pragma unroll
                for (int mf = 0; mf < 2; ++mf)
#pragma unroll
                    for (int df = 0; df < 4; ++df)
                        o[mf][df] = __builtin_amdgcn_mfma_f32_16x16x32_bf16(pf[mf], vf[df], o[mf][df], 0, 0, 0);
            }
        }
    }

    // normalize + store att (bf16)
#pragma unroll
    for (int mf = 0; mf < 2; ++mf)
#pragma unroll
        for (int df = 0; df < 4; ++df)
#pragma unroll
            for (int r = 0; r < 4; ++r) {
                int qg = wq0 + mf * 16 + lg * 4 + r;
                float v = o[mf][df][r] / l_run[mf][r];
                att[baseQK + (size_t)qg * CC + df * 16 + lr] = __float2bfloat16(v);
            }
}

// ---------------------------------------------------------------------------
extern "C" void kernel_launch(void* const* d_in, const int* in_sizes, int n_in,
                              void* d_out, int out_size, void* d_ws, size_t ws_size,
                              hipStream_t stream) {
    const float* x  = (const float*)d_in[0];
    // d_in[1] = attention_mask: no-op in the reference
    const float* Wq = (const float*)d_in[2];
    const float* Wk = (const float*)d_in[3];
    const float* Wv = (const float*)d_in[4];
    const float* Wp = (const float*)d_in[5];
    const float* bp = (const float*)d_in[6];
    float* out = (float*)d_out;

    __hip_bfloat16* ws  = (__hip_bfloat16*)d_ws;
    __hip_bfloat16* xb  = ws;                       // MM*CC
    __hip_bfloat16* wqt = xb  + (size_t)MM * CC;    // CC*CC each, contiguous (QKV concat)
    __hip_bfloat16* wkt = wqt + (size_t)CC * CC;
    __hip_bfloat16* wvt = wkt + (size_t)CC * CC;
    __hip_bfloat16* wpt = wvt + (size_t)CC * CC;
    __hip_bfloat16* Qb  = wpt + (size_t)CC * CC;    // MM*CC
    __hip_bfloat16* Kb  = Qb  + (size_t)MM * CC;    // MM*CC
    __hip_bfloat16* VtG = Kb  + (size_t)MM * CC;    // [B][H][D][T]
    __hip_bfloat16* att = VtG + (size_t)MM * CC;    // MM*CC

    // 1) conversions
    conv_bf16<<<(MM * CC / 4 + 255) / 256, 256, 0, stream>>>(x, xb, MM * CC / 4);
    dim3 tg(CC / 32, CC / 32);
    transpose_conv<<<tg, 256, 0, stream>>>(Wq, wqt);
    transpose_conv<<<tg, 256, 0, stream>>>(Wk, wkt);
    transpose_conv<<<tg, 256, 0, stream>>>(Wv, wvt);
    transpose_conv<<<tg, 256, 0, stream>>>(Wp, wpt);

    // 2) fused QKV projection (N=3072; V written per-head transposed)
    dim3 gq(3 * CC / 128, MM / 128);  // (24, 32)
    gemm_bt<1><<<gq, 256, 0, stream>>>(xb, wqt, Qb, Kb, VtG, nullptr, MM, 3 * CC, CC);

    // 3) causal attention
    dim3 ag(TT / 128, HH, BB);
    attn_kernel<<<ag, 256, 0, stream>>>(Qb, Kb, VtG, att);

    // 4) output projection + bias (fp32 out)
    dim3 gp(CC / 128, MM / 128);  // (8, 32)
    gemm_bt<2><<<gp, 256, 0, stream>>>(att, wpt, out, nullptr, nullptr, bp, MM, CC, CC);
}

// Round 3
// 215.080 us; speedup vs baseline: 1.6611x; 1.1461x over previous
//
#include <hip/hip_runtime.h>
#include <hip/hip_bf16.h>
#include <stdint.h>

// Problem constants (B=2, T=2048, C=1024, H=16, d=64)
#define BB 2
#define TT 2048
#define CC 1024
#define HH 16
#define DD 64
#define MM (BB*TT)   // 4096 rows

// log2(e) / sqrt(C) : folded into Q at projection time; softmax runs in exp2 domain
#define C2SCALE 0.045084220027780106f

typedef __bf16 bf16x8 __attribute__((ext_vector_type(8)));
typedef float f32x4 __attribute__((ext_vector_type(4)));

// async 16B global -> LDS (dest must be linear: wave-uniform base + lane*16)
__device__ __forceinline__ void load_lds16(const void* g, void* l) {
    __builtin_amdgcn_global_load_lds((const __attribute__((address_space(1))) uint32_t*)g,
                                     (__attribute__((address_space(3))) uint32_t*)l,
                                     16, 0, 0);
}

// ---------------------------------------------------------------------------
// x (fp32) -> bf16, vectorized 4-wide
__global__ __launch_bounds__(256)
void conv_bf16(const float* __restrict__ in, __hip_bfloat16* __restrict__ out, int n4) {
    int i = blockIdx.x * 256 + threadIdx.x;
    if (i >= n4) return;
    float4 f = reinterpret_cast<const float4*>(in)[i];
    union { __hip_bfloat16 h[4]; uint2 u; } cv;
    cv.h[0] = __float2bfloat16(f.x);
    cv.h[1] = __float2bfloat16(f.y);
    cv.h[2] = __float2bfloat16(f.z);
    cv.h[3] = __float2bfloat16(f.w);
    reinterpret_cast<uint2*>(out)[i] = cv.u;
}

// W (CxC fp32, row-major [k][n]) -> Wt (bf16, [n][k]) via LDS tile transpose
__global__ __launch_bounds__(256)
void transpose_conv(const float* __restrict__ W, __hip_bfloat16* __restrict__ Wt) {
    __shared__ float t[32][33];
    int kt = blockIdx.x * 32, nt = blockIdx.y * 32;
    int tx = threadIdx.x & 31, ty = threadIdx.x >> 5;  // 32 x 8
#pragma unroll
    for (int r = 0; r < 32; r += 8)
        t[ty + r][tx] = W[(size_t)(kt + ty + r) * CC + nt + tx];
    __syncthreads();
#pragma unroll
    for (int r = 0; r < 32; r += 8)
        Wt[(size_t)(nt + ty + r) * CC + kt + tx] = __float2bfloat16(t[tx][ty + r]);
}

// ---------------------------------------------------------------------------
// C[M][N] = A[M][K] @ Bt[N][K]^T, bf16, MFMA 16x16x32, tile 128x128, BK=64.
// MODE 1: fused QKV (N=3072): n<1024 -> Q (out0, scaled by C2SCALE),
//         <2048 -> K (out1), else V transposed per-head: out2[b][h][d][T].
// MODE 2: fp32 out0 + bias.
template <int MODE>
__global__ __launch_bounds__(256)
void gemm_bt(const __hip_bfloat16* __restrict__ A,
             const __hip_bfloat16* __restrict__ Bt,
             void* __restrict__ out0, void* __restrict__ out1, void* __restrict__ out2,
             const float* __restrict__ bias,
             int M, int N, int K) {
    __shared__ __hip_bfloat16 As[128 * 64];
    __shared__ __hip_bfloat16 Bs[128 * 64];

    const int tid = threadIdx.x;
    const int wave = tid >> 6, lane = tid & 63;
    const int lg = lane >> 4, lr = lane & 15;
    const int wm = wave >> 1, wn = wave & 1;
    const int bm0 = blockIdx.y * 128, bn0 = blockIdx.x * 128;

    f32x4 acc[4][4] = {};

    for (int k0 = 0; k0 < K; k0 += 64) {
        __syncthreads();
#pragma unroll
        for (int it = 0; it < 4; ++it) {
            int c = it * 256 + tid;
            int row = c >> 3, sub = c & 7;
            int g = sub ^ (row & 7);
            load_lds16((const char*)(A + (size_t)(bm0 + row) * K + k0) + g * 16,
                       (char*)As + c * 16);
        }
#pragma unroll
        for (int it = 0; it < 4; ++it) {
            int c = it * 256 + tid;
            int row = c >> 3, sub = c & 7;
            int g = sub ^ (row & 7);
            load_lds16((const char*)(Bt + (size_t)(bn0 + row) * K + k0) + g * 16,
                       (char*)Bs + c * 16);
        }
        __syncthreads();

        bf16x8 af[2][4], bf[2][4];
#pragma unroll
        for (int kk = 0; kk < 2; ++kk) {
#pragma unroll
            for (int m = 0; m < 4; ++m) {
                int row = wm * 64 + m * 16 + lr;
                af[kk][m] = *(const bf16x8*)((const char*)As + row * 128 + (((kk * 4 + lg) ^ (row & 7)) * 16));
            }
#pragma unroll
            for (int n = 0; n < 4; ++n) {
                int row = wn * 64 + n * 16 + lr;
                bf[kk][n] = *(const bf16x8*)((const char*)Bs + row * 128 + (((kk * 4 + lg) ^ (row & 7)) * 16));
            }
        }
#pragma unroll
        for (int kk = 0; kk < 2; ++kk)
#pragma unroll
            for (int m = 0; m < 4; ++m)
#pragma unroll
                for (int n = 0; n < 4; ++n)
                    acc[m][n] = __builtin_amdgcn_mfma_f32_16x16x32_bf16(af[kk][m], bf[kk][n], acc[m][n], 0, 0, 0);
    }

    // epilogue: C/D layout col = lane&15, row = (lane>>4)*4 + reg
#pragma unroll
    for (int m = 0; m < 4; ++m)
#pragma unroll
        for (int n = 0; n < 4; ++n) {
            int row0 = bm0 + wm * 64 + m * 16 + lg * 4;
            int colf = bn0 + wn * 64 + n * 16 + lr;
            if (MODE == 2) {
#pragma unroll
                for (int r = 0; r < 4; ++r)
                    ((float*)out0)[(size_t)(row0 + r) * N + colf] = acc[m][n][r] + bias[colf];
            } else {
                int which = colf >> 10, col = colf & 1023;
                if (which < 2) {
                    __hip_bfloat16* o = which ? (__hip_bfloat16*)out1 : (__hip_bfloat16*)out0;
                    float sc = which ? 1.0f : C2SCALE;  // Q pre-scaled for exp2-domain softmax
#pragma unroll
                    for (int r = 0; r < 4; ++r)
                        o[(size_t)(row0 + r) * 1024 + col] = __float2bfloat16(acc[m][n][r] * sc);
                } else {
                    int hh = col >> 6, dd = col & 63;
                    int bI = row0 >> 11, tt = row0 & 2047;
                    union { __hip_bfloat16 h[4]; uint2 u; } pk;
#pragma unroll
                    for (int r = 0; r < 4; ++r) pk.h[r] = __float2bfloat16(acc[m][n][r]);
                    *(uint2*)((__hip_bfloat16*)out2 + ((size_t)(bI * HH + hh) * DD + dd) * TT + tt) = pk.u;
                }
            }
        }
}

// ---------------------------------------------------------------------------
// Flash-style causal attention, swapped-QK^T softmax + double-buffered staging.
// 1-D grid of 512: id = (hb&7) + 8*(qt + 16*(hb>>3)); b==1 flips qt for balance.
// 4 waves own 32 q-rows each; KV tiles of 64; V pre-transposed [b][h][d][T].
__global__ __launch_bounds__(256)
void attn_kernel(const __hip_bfloat16* __restrict__ Q,
                 const __hip_bfloat16* __restrict__ K,
                 const __hip_bfloat16* __restrict__ Vt,
                 __hip_bfloat16* __restrict__ att) {
    __shared__ __hip_bfloat16 Ks[2][64 * 64];   // [kv][d], XOR-swizzled
    __shared__ __hip_bfloat16 Vs[2][64 * 64];   // [d][kv], XOR-swizzled
    __shared__ __hip_bfloat16 Pl[4][32 * 72];   // per-wave P: [q_local][kv], padded

    const int tid = threadIdx.x;
    const int wave = tid >> 6, lane = tid & 63;
    const int lg = lane >> 4, lr = lane & 15;

    // XCD-contiguous decode: all qt-blocks of one (h,b) land on one XCD
    int id = blockIdx.x;
    int rest = id >> 3;
    int qt = rest & 15;
    int hb = (id & 7) + ((rest >> 4) << 3);
    const int h = hb & 15, b = hb >> 4;
    if (b & 1) qt = 15 - qt;  // complement pairing -> balanced CUs

    const size_t baseQK = ((size_t)b * TT) * CC + (size_t)h * DD;
    const __hip_bfloat16* Vth = Vt + ((size_t)(b * HH + h)) * DD * TT;
    const int wq0 = qt * 128 + wave * 32;

    bf16x8 qf[2][2];
#pragma unroll
    for (int mf = 0; mf < 2; ++mf)
#pragma unroll
        for (int kf = 0; kf < 2; ++kf)
            qf[mf][kf] = *(const bf16x8*)&Q[baseQK + (size_t)(wq0 + mf * 16 + lr) * CC + kf * 32 + lg * 8];

    float m_run[2], l_run[2];
    f32x4 o[2][4] = {};
#pragma unroll
    for (int mf = 0; mf < 2; ++mf) { m_run[mf] = -1e30f; l_run[mf] = 0.f; }

    const int nkt = qt * 2 + 2;

    // cooperative stage of one 64-kv tile (K + V^T) into buffer `bufi`
    auto stage = [&](int bufi, int kv0) {
#pragma unroll
        for (int it = 0; it < 2; ++it) {
            int c = it * 256 + tid;
            int row = c >> 3, sub = c & 7;
            int g = sub ^ (row & 7);
            load_lds16((const char*)(K + baseQK + (size_t)(kv0 + row) * CC) + g * 16,
                       (char*)Ks[bufi] + c * 16);
            load_lds16((const char*)(Vth + (size_t)row * TT + kv0) + g * 16,
                       (char*)Vs[bufi] + c * 16);
        }
    };

    stage(0, 0);  // prologue

    for (int kt = 0; kt < nkt; ++kt) {
        const int kv0 = kt * 64;
        __syncthreads();                      // drains tile kt's loads (vmcnt 0)
        if (kt + 1 < nkt) stage((kt + 1) & 1, kv0 + 64);  // prefetch under compute
        const char* Kb = (const char*)Ks[kt & 1];
        const char* Vb = (const char*)Vs[kt & 1];

        if (kv0 > wq0 + 31) continue;  // fully-masked for this wave (barriers stay aligned)

        // S^T = K @ Q^T : s[mf][nf] row = kv_local (nf*16+lg*4+r), col = q_local (mf*16+lr)
        f32x4 s[2][4] = {};
#pragma unroll
        for (int kf = 0; kf < 2; ++kf) {
            bf16x8 kfr[4];
#pragma unroll
            for (int nf = 0; nf < 4; ++nf)
                kfr[nf] = *(const bf16x8*)(Kb + (nf * 16 + lr) * 128 + (((kf * 4 + lg) ^ (lr & 7)) * 16));
#pragma unroll
            for (int mf = 0; mf < 2; ++mf)
#pragma unroll
                for (int nf = 0; nf < 4; ++nf)
                    s[mf][nf] = __builtin_amdgcn_mfma_f32_16x16x32_bf16(kfr[nf], qf[mf][kf], s[mf][nf], 0, 0, 0);
        }

        const bool needMask = (kv0 + 63 > wq0);
#pragma unroll
        for (int mf = 0; mf < 2; ++mf) {
            const int qg = wq0 + mf * 16 + lr;
            // mask + in-lane max over this lane's 16 kv values
            float mx = -1e30f;
#pragma unroll
            for (int nf = 0; nf < 4; ++nf)
#pragma unroll
                for (int r = 0; r < 4; ++r) {
                    float sv = s[mf][nf][r];
                    if (needMask) {
                        int kvg = kv0 + nf * 16 + lg * 4 + r;
                        sv = (kvg > qg) ? -1e30f : sv;
                        s[mf][nf][r] = sv;
                    }
                    mx = fmaxf(mx, sv);
                }
            mx = fmaxf(mx, __shfl_xor(mx, 16, 64));
            mx = fmaxf(mx, __shfl_xor(mx, 32, 64));
            float mold = m_run[mf];
            float mnew = fmaxf(mold, mx);
            float sc = __builtin_amdgcn_exp2f(mold - mnew);
            float rsum = 0.f;
#pragma unroll
            for (int nf = 0; nf < 4; ++nf)
#pragma unroll
                for (int r = 0; r < 4; ++r) {
                    float p = __builtin_amdgcn_exp2f(s[mf][nf][r] - mnew);
                    s[mf][nf][r] = p;
                    rsum += p;
                }
            rsum += __shfl_xor(rsum, 16, 64);
            rsum += __shfl_xor(rsum, 32, 64);
            l_run[mf] = l_run[mf] * sc + rsum;
            m_run[mf] = mnew;
            // broadcast sc into O-fragment row layout (row = lg*4+r) and rescale
#pragma unroll
            for (int r = 0; r < 4; ++r) {
                float sco = __shfl(sc, lg * 4 + r, 64);
#pragma unroll
                for (int df = 0; df < 4; ++df) o[mf][df][r] *= sco;
            }
        }

        // P^T regs -> per-wave LDS as P[q][kv], then PV
        __hip_bfloat16* Pw = &Pl[wave][0];
#pragma unroll
        for (int mf = 0; mf < 2; ++mf)
#pragma unroll
            for (int nf = 0; nf < 4; ++nf)
#pragma unroll
                for (int r = 0; r < 4; ++r)
                    Pw[(mf * 16 + lr) * 72 + nf * 16 + lg * 4 + r] = __float2bfloat16(s[mf][nf][r]);

#pragma unroll
        for (int ks = 0; ks < 2; ++ks) {
            bf16x8 pf[2], vf[4];
#pragma unroll
            for (int mf = 0; mf < 2; ++mf)
                pf[mf] = *(const bf16x8*)&Pw[(mf * 16 + lr) * 72 + ks * 32 + lg * 8];
#pragma unroll
            for (int df = 0; df < 4; ++df)
                vf[df] = *(const bf16x8*)(Vb + (df * 16 + lr) * 128 + (((ks * 4 + lg) ^ (lr & 7)) * 16));
#pragma unroll
            for (int mf = 0; mf < 2; ++mf)
#pragma unroll
                for (int df = 0; df < 4; ++df)
                    o[mf][df] = __builtin_amdgcn_mfma_f32_16x16x32_bf16(pf[mf], vf[df], o[mf][df], 0, 0, 0);
        }
    }

    // normalize + store att (bf16); l broadcast into O-row layout
#pragma unroll
    for (int mf = 0; mf < 2; ++mf)
#pragma unroll
        for (int r = 0; r < 4; ++r) {
            float lo = __shfl(l_run[mf], lg * 4 + r, 64);
            float inv = 1.0f / lo;
            int qg = wq0 + mf * 16 + lg * 4 + r;
#pragma unroll
            for (int df = 0; df < 4; ++df)
                att[baseQK + (size_t)qg * CC + df * 16 + lr] = __float2bfloat16(o[mf][df][r] * inv);
        }
}

// ---------------------------------------------------------------------------
extern "C" void kernel_launch(void* const* d_in, const int* in_sizes, int n_in,
                              void* d_out, int out_size, void* d_ws, size_t ws_size,
                              hipStream_t stream) {
    const float* x  = (const float*)d_in[0];
    // d_in[1] = attention_mask: no-op in the reference
    const float* Wq = (const float*)d_in[2];
    const float* Wk = (const float*)d_in[3];
    const float* Wv = (const float*)d_in[4];
    const float* Wp = (const float*)d_in[5];
    const float* bp = (const float*)d_in[6];
    float* out = (float*)d_out;

    __hip_bfloat16* ws  = (__hip_bfloat16*)d_ws;
    __hip_bfloat16* xb  = ws;                       // MM*CC
    __hip_bfloat16* wqt = xb  + (size_t)MM * CC;    // CC*CC each, contiguous (QKV concat)
    __hip_bfloat16* wkt = wqt + (size_t)CC * CC;
    __hip_bfloat16* wvt = wkt + (size_t)CC * CC;
    __hip_bfloat16* wpt = wvt + (size_t)CC * CC;
    __hip_bfloat16* Qb  = wpt + (size_t)CC * CC;    // MM*CC
    __hip_bfloat16* Kb  = Qb  + (size_t)MM * CC;    // MM*CC
    __hip_bfloat16* VtG = Kb  + (size_t)MM * CC;    // [B][H][D][T]
    __hip_bfloat16* att = VtG + (size_t)MM * CC;    // MM*CC

    // 1) conversions
    conv_bf16<<<(MM * CC / 4 + 255) / 256, 256, 0, stream>>>(x, xb, MM * CC / 4);
    dim3 tg(CC / 32, CC / 32);
    transpose_conv<<<tg, 256, 0, stream>>>(Wq, wqt);
    transpose_conv<<<tg, 256, 0, stream>>>(Wk, wkt);
    transpose_conv<<<tg, 256, 0, stream>>>(Wv, wvt);
    transpose_conv<<<tg, 256, 0, stream>>>(Wp, wpt);

    // 2) fused QKV projection (N=3072; Q pre-scaled; V written per-head transposed)
    dim3 gq(3 * CC / 128, MM / 128);  // (24, 32)
    gemm_bt<1><<<gq, 256, 0, stream>>>(xb, wqt, Qb, Kb, VtG, nullptr, MM, 3 * CC, CC);

    // 3) causal attention (1-D grid, XCD-contiguous mapping)
    attn_kernel<<<dim3(512), 256, 0, stream>>>(Qb, Kb, VtG, att);

    // 4) output projection + bias (fp32 out)
    dim3 gp(CC / 128, MM / 128);  // (8, 32)
    gemm_bt<2><<<gp, 256, 0, stream>>>(att, wpt, out, nullptr, nullptr, bp, MM, CC, CC);
}

// Round 4
// 193.123 us; speedup vs baseline: 1.8500x; 1.1137x over previous
//
#include <hip/hip_runtime.h>
#include <hip/hip_bf16.h>
#include <stdint.h>

// Problem constants (B=2, T=2048, C=1024, H=16, d=64)
#define BB 2
#define TT 2048
#define CC 1024
#define HH 16
#define DD 64
#define MM (BB*TT)   // 4096 rows

// log2(e) / sqrt(C) : folded into Q at projection time; softmax runs in exp2 domain
#define C2SCALE 0.045084220027780106f

typedef __bf16 bf16x8 __attribute__((ext_vector_type(8)));
typedef float f32x4 __attribute__((ext_vector_type(4)));

// async 16B global -> LDS (dest must be linear: wave-uniform base + lane*16)
__device__ __forceinline__ void load_lds16(const void* g, void* l) {
    __builtin_amdgcn_global_load_lds((const __attribute__((address_space(1))) uint32_t*)g,
                                     (__attribute__((address_space(3))) uint32_t*)l,
                                     16, 0, 0);
}

// ---------------------------------------------------------------------------
// x (fp32) -> bf16, vectorized 4-wide
__global__ __launch_bounds__(256)
void conv_bf16(const float* __restrict__ in, __hip_bfloat16* __restrict__ out, int n4) {
    int i = blockIdx.x * 256 + threadIdx.x;
    if (i >= n4) return;
    float4 f = reinterpret_cast<const float4*>(in)[i];
    union { __hip_bfloat16 h[4]; uint2 u; } cv;
    cv.h[0] = __float2bfloat16(f.x);
    cv.h[1] = __float2bfloat16(f.y);
    cv.h[2] = __float2bfloat16(f.z);
    cv.h[3] = __float2bfloat16(f.w);
    reinterpret_cast<uint2*>(out)[i] = cv.u;
}

// All four W (CxC fp32, row-major [k][n]) -> Wt (bf16, [n][k]); z selects matrix.
__global__ __launch_bounds__(256)
void transpose_conv4(const float* __restrict__ W0, const float* __restrict__ W1,
                     const float* __restrict__ W2, const float* __restrict__ W3,
                     __hip_bfloat16* __restrict__ out) {
    __shared__ float t[32][33];
    const int z = blockIdx.z;
    const float* W = (z == 0) ? W0 : (z == 1) ? W1 : (z == 2) ? W2 : W3;
    __hip_bfloat16* Wt = out + (size_t)z * CC * CC;
    int kt = blockIdx.x * 32, nt = blockIdx.y * 32;
    int tx = threadIdx.x & 31, ty = threadIdx.x >> 5;  // 32 x 8
#pragma unroll
    for (int r = 0; r < 32; r += 8)
        t[ty + r][tx] = W[(size_t)(kt + ty + r) * CC + nt + tx];
    __syncthreads();
#pragma unroll
    for (int r = 0; r < 32; r += 8)
        Wt[(size_t)(nt + ty + r) * CC + kt + tx] = __float2bfloat16(t[tx][ty + r]);
}

// ---------------------------------------------------------------------------
// C[M][N] = A[M][K] @ Bt[N][K]^T, bf16, MFMA 16x16x32, tile 128x128, BK=64.
// MODE 1: fused QKV (N=3072): n<1024 -> Q (out0, scaled by C2SCALE),
//         <2048 -> K (out1), else V transposed per-head: out2[b][h][d][T].
// MODE 2: fp32 out0 + bias.
template <int MODE>
__global__ __launch_bounds__(256)
void gemm_bt(const __hip_bfloat16* __restrict__ A,
             const __hip_bfloat16* __restrict__ Bt,
             void* __restrict__ out0, void* __restrict__ out1, void* __restrict__ out2,
             const float* __restrict__ bias,
             int M, int N, int K) {
    __shared__ __hip_bfloat16 As[128 * 64];
    __shared__ __hip_bfloat16 Bs[128 * 64];

    const int tid = threadIdx.x;
    const int wave = tid >> 6, lane = tid & 63;
    const int lg = lane >> 4, lr = lane & 15;
    const int wm = wave >> 1, wn = wave & 1;
    const int bm0 = blockIdx.y * 128, bn0 = blockIdx.x * 128;

    f32x4 acc[4][4] = {};

    for (int k0 = 0; k0 < K; k0 += 64) {
        __syncthreads();
#pragma unroll
        for (int it = 0; it < 4; ++it) {
            int c = it * 256 + tid;
            int row = c >> 3, sub = c & 7;
            int g = sub ^ (row & 7);
            load_lds16((const char*)(A + (size_t)(bm0 + row) * K + k0) + g * 16,
                       (char*)As + c * 16);
        }
#pragma unroll
        for (int it = 0; it < 4; ++it) {
            int c = it * 256 + tid;
            int row = c >> 3, sub = c & 7;
            int g = sub ^ (row & 7);
            load_lds16((const char*)(Bt + (size_t)(bn0 + row) * K + k0) + g * 16,
                       (char*)Bs + c * 16);
        }
        __syncthreads();

        bf16x8 af[2][4], bf[2][4];
#pragma unroll
        for (int kk = 0; kk < 2; ++kk) {
#pragma unroll
            for (int m = 0; m < 4; ++m) {
                int row = wm * 64 + m * 16 + lr;
                af[kk][m] = *(const bf16x8*)((const char*)As + row * 128 + (((kk * 4 + lg) ^ (row & 7)) * 16));
            }
#pragma unroll
            for (int n = 0; n < 4; ++n) {
                int row = wn * 64 + n * 16 + lr;
                bf[kk][n] = *(const bf16x8*)((const char*)Bs + row * 128 + (((kk * 4 + lg) ^ (row & 7)) * 16));
            }
        }
#pragma unroll
        for (int kk = 0; kk < 2; ++kk)
#pragma unroll
            for (int m = 0; m < 4; ++m)
#pragma unroll
                for (int n = 0; n < 4; ++n)
                    acc[m][n] = __builtin_amdgcn_mfma_f32_16x16x32_bf16(af[kk][m], bf[kk][n], acc[m][n], 0, 0, 0);
    }

    // epilogue: C/D layout col = lane&15, row = (lane>>4)*4 + reg
#pragma unroll
    for (int m = 0; m < 4; ++m)
#pragma unroll
        for (int n = 0; n < 4; ++n) {
            int row0 = bm0 + wm * 64 + m * 16 + lg * 4;
            int colf = bn0 + wn * 64 + n * 16 + lr;
            if (MODE == 2) {
#pragma unroll
                for (int r = 0; r < 4; ++r)
                    ((float*)out0)[(size_t)(row0 + r) * N + colf] = acc[m][n][r] + bias[colf];
            } else {
                int which = colf >> 10, col = colf & 1023;
                if (which < 2) {
                    __hip_bfloat16* o = which ? (__hip_bfloat16*)out1 : (__hip_bfloat16*)out0;
                    float sc = which ? 1.0f : C2SCALE;  // Q pre-scaled for exp2-domain softmax
#pragma unroll
                    for (int r = 0; r < 4; ++r)
                        o[(size_t)(row0 + r) * 1024 + col] = __float2bfloat16(acc[m][n][r] * sc);
                } else {
                    int hh = col >> 6, dd = col & 63;
                    int bI = row0 >> 11, tt = row0 & 2047;
                    union { __hip_bfloat16 h[4]; uint2 u; } pk;
#pragma unroll
                    for (int r = 0; r < 4; ++r) pk.h[r] = __float2bfloat16(acc[m][n][r]);
                    *(uint2*)((__hip_bfloat16*)out2 + ((size_t)(bI * HH + hh) * DD + dd) * TT + tt) = pk.u;
                }
            }
        }
}

// ---------------------------------------------------------------------------
// Flash-style causal attention: 8 waves x 16 q-rows (512 threads), swapped
// QK^T softmax in exp2 domain, defer-max, double-buffered K/V staging.
// 1-D grid of 512: id = (hb&7) + 8*(qt + 16*(hb>>3)); b==1 flips qt.
__global__ __launch_bounds__(512)
void attn_kernel(const __hip_bfloat16* __restrict__ Q,
                 const __hip_bfloat16* __restrict__ K,
                 const __hip_bfloat16* __restrict__ Vt,
                 __hip_bfloat16* __restrict__ att) {
    __shared__ __hip_bfloat16 Ks[2][64 * 64];   // [kv][d], XOR-swizzled
    __shared__ __hip_bfloat16 Vs[2][64 * 64];   // [d][kv], XOR-swizzled
    __shared__ __hip_bfloat16 Pl[8][16 * 72];   // per-wave P: [q_local][kv], padded

    const int tid = threadIdx.x;
    const int wave = tid >> 6, lane = tid & 63;
    const int lg = lane >> 4, lr = lane & 15;

    // XCD-contiguous decode: all qt-blocks of one (h,b) land on one XCD
    int id = blockIdx.x;
    int rest = id >> 3;
    int qt = rest & 15;
    int hb = (id & 7) + ((rest >> 4) << 3);
    const int h = hb & 15, b = hb >> 4;
    if (b & 1) qt = 15 - qt;  // complement pairing -> balanced CUs

    const size_t baseQK = ((size_t)b * TT) * CC + (size_t)h * DD;
    const __hip_bfloat16* Vth = Vt + ((size_t)(b * HH + h)) * DD * TT;
    const int wq0 = qt * 128 + wave * 16;

    bf16x8 qf[2];
#pragma unroll
    for (int kf = 0; kf < 2; ++kf)
        qf[kf] = *(const bf16x8*)&Q[baseQK + (size_t)(wq0 + lr) * CC + kf * 32 + lg * 8];

    float m_run = -1e30f, l_run = 0.f;
    f32x4 o[4] = {};

    const int nkt = qt * 2 + 2;

    // stage one 64-kv tile (K + V^T): 512 threads x 1 chunk of 16B per matrix
    auto stage = [&](int bufi, int kv0) {
        int row = tid >> 3, sub = tid & 7;
        int g = sub ^ (row & 7);
        load_lds16((const char*)(K + baseQK + (size_t)(kv0 + row) * CC) + g * 16,
                   (char*)Ks[bufi] + tid * 16);
        load_lds16((const char*)(Vth + (size_t)row * TT + kv0) + g * 16,
                   (char*)Vs[bufi] + tid * 16);
    };

    stage(0, 0);  // prologue

    for (int kt = 0; kt < nkt; ++kt) {
        const int kv0 = kt * 64;
        __syncthreads();                      // tile kt's loads complete
        if (kt + 1 < nkt) stage((kt + 1) & 1, kv0 + 64);  // prefetch under compute
        const char* Kb = (const char*)Ks[kt & 1];
        const char* Vb = (const char*)Vs[kt & 1];

        if (kv0 > wq0 + 15) continue;  // fully-masked for this wave

        // S^T = K @ Q^T : s[nf] row = kv_local (nf*16+lg*4+r), col = q_local (lr)
        f32x4 s[4] = {};
#pragma unroll
        for (int kf = 0; kf < 2; ++kf) {
            bf16x8 kfr[4];
#pragma unroll
            for (int nf = 0; nf < 4; ++nf)
                kfr[nf] = *(const bf16x8*)(Kb + (nf * 16 + lr) * 128 + (((kf * 4 + lg) ^ (lr & 7)) * 16));
#pragma unroll
            for (int nf = 0; nf < 4; ++nf)
                s[nf] = __builtin_amdgcn_mfma_f32_16x16x32_bf16(kfr[nf], qf[kf], s[nf], 0, 0, 0);
        }

        const bool needMask = (kv0 + 63 > wq0);
        const int qg = wq0 + lr;
        float mx = -1e30f;
#pragma unroll
        for (int nf = 0; nf < 4; ++nf)
#pragma unroll
            for (int r = 0; r < 4; ++r) {
                float sv = s[nf][r];
                if (needMask) {
                    int kvg = kv0 + nf * 16 + lg * 4 + r;
                    sv = (kvg > qg) ? -1e30f : sv;
                    s[nf][r] = sv;
                }
                mx = fmaxf(mx, sv);
            }
        mx = fmaxf(mx, __shfl_xor(mx, 16, 64));
        mx = fmaxf(mx, __shfl_xor(mx, 32, 64));

        // defer-max (T13): only rescale when max grows by > 8 (exp2 domain)
        bool grow = __any(mx > m_run + 8.0f);
        float sc = 0.0f;
        if (grow) {
            float mnew = fmaxf(m_run, mx);
            sc = __builtin_amdgcn_exp2f(m_run - mnew);
            m_run = mnew;
        }
        float rsum = 0.f;
#pragma unroll
        for (int nf = 0; nf < 4; ++nf)
#pragma unroll
            for (int r = 0; r < 4; ++r) {
                float p = __builtin_amdgcn_exp2f(s[nf][r] - m_run);
                s[nf][r] = p;
                rsum += p;
            }
        rsum += __shfl_xor(rsum, 16, 64);
        rsum += __shfl_xor(rsum, 32, 64);
        if (grow) {
            l_run = l_run * sc + rsum;
#pragma unroll
            for (int r = 0; r < 4; ++r) {
                float sco = __shfl(sc, lg * 4 + r, 64);
#pragma unroll
                for (int df = 0; df < 4; ++df) o[df][r] *= sco;
            }
        } else {
            l_run += rsum;
        }

        // P^T regs -> per-wave LDS as P[q][kv] (packed b64 writes), then PV
        __hip_bfloat16* Pw = &Pl[wave][0];
#pragma unroll
        for (int nf = 0; nf < 4; ++nf) {
            union { __hip_bfloat16 h[4]; uint2 u; } pk;
#pragma unroll
            for (int r = 0; r < 4; ++r) pk.h[r] = __float2bfloat16(s[nf][r]);
            *(uint2*)&Pw[lr * 72 + nf * 16 + lg * 4] = pk.u;
        }

#pragma unroll
        for (int ks = 0; ks < 2; ++ks) {
            bf16x8 pf = *(const bf16x8*)&Pw[lr * 72 + ks * 32 + lg * 8];
            bf16x8 vf[4];
#pragma unroll
            for (int df = 0; df < 4; ++df)
                vf[df] = *(const bf16x8*)(Vb + (df * 16 + lr) * 128 + (((ks * 4 + lg) ^ (lr & 7)) * 16));
#pragma unroll
            for (int df = 0; df < 4; ++df)
                o[df] = __builtin_amdgcn_mfma_f32_16x16x32_bf16(pf, vf[df], o[df], 0, 0, 0);
        }
    }

    // normalize + store att (bf16); l broadcast into O-row layout (row = lg*4+r)
#pragma unroll
    for (int r = 0; r < 4; ++r) {
        float lo = __shfl(l_run, lg * 4 + r, 64);
        float inv = 1.0f / lo;
        int qg = wq0 + lg * 4 + r;
#pragma unroll
        for (int df = 0; df < 4; ++df)
            att[baseQK + (size_t)qg * CC + df * 16 + lr] = __float2bfloat16(o[df][r] * inv);
    }
}

// ---------------------------------------------------------------------------
extern "C" void kernel_launch(void* const* d_in, const int* in_sizes, int n_in,
                              void* d_out, int out_size, void* d_ws, size_t ws_size,
                              hipStream_t stream) {
    const float* x  = (const float*)d_in[0];
    // d_in[1] = attention_mask: no-op in the reference
    const float* Wq = (const float*)d_in[2];
    const float* Wk = (const float*)d_in[3];
    const float* Wv = (const float*)d_in[4];
    const float* Wp = (const float*)d_in[5];
    const float* bp = (const float*)d_in[6];
    float* out = (float*)d_out;

    __hip_bfloat16* ws  = (__hip_bfloat16*)d_ws;
    __hip_bfloat16* xb  = ws;                       // MM*CC
    __hip_bfloat16* wqt = xb  + (size_t)MM * CC;    // CC*CC each, contiguous (QKV concat + Wp)
    __hip_bfloat16* wpt = wqt + 3 * (size_t)CC * CC;
    __hip_bfloat16* Qb  = wpt + (size_t)CC * CC;    // MM*CC
    __hip_bfloat16* Kb  = Qb  + (size_t)MM * CC;    // MM*CC
    __hip_bfloat16* VtG = Kb  + (size_t)MM * CC;    // [B][H][D][T]
    __hip_bfloat16* att = VtG + (size_t)MM * CC;    // MM*CC

    // 1) conversions (fused weight transposes)
    conv_bf16<<<(MM * CC / 4 + 255) / 256, 256, 0, stream>>>(x, xb, MM * CC / 4);
    transpose_conv4<<<dim3(CC / 32, CC / 32, 4), 256, 0, stream>>>(Wq, Wk, Wv, Wp, wqt);

    // 2) fused QKV projection (N=3072; Q pre-scaled; V written per-head transposed)
    dim3 gq(3 * CC / 128, MM / 128);  // (24, 32)
    gemm_bt<1><<<gq, 256, 0, stream>>>(xb, wqt, Qb, Kb, VtG, nullptr, MM, 3 * CC, CC);

    // 3) causal attention (1-D grid, XCD-contiguous mapping, 512-thread blocks)
    attn_kernel<<<dim3(512), 512, 0, stream>>>(Qb, Kb, VtG, att);

    // 4) output projection + bias (fp32 out)
    dim3 gp(CC / 128, MM / 128);  // (8, 32)
    gemm_bt<2><<<gp, 256, 0, stream>>>(att, wpt, out, nullptr, nullptr, bp, MM, CC, CC);
}